// Round 1
// 79.194 us; speedup vs baseline: 1.0225x; 1.0225x over previous
//
#include <hip/hip_runtime.h>

// MPSLayer: out[b,o] = s_b * q[o] + bias[o]
//   s_b = prod_i x[b,i]
//   u^T = 1^T prod_i C_i   (16 segment products of 16 cores, then folded)
//   q[o] = sum_r u[r] * P2[r,o],  P2[r,o] = sum_l proj[r,l,o]
//
// ws layout (floats):
//   [0,     16384) : M_seg[16][32][32]   (row l, col c)
//   [16384, 32768) : P2[32][512]
//   [32768, 33792) : s[1024]

#define NSEG   16
#define SEGLEN 16

__global__ __launch_bounds__(512) void mps_k1(const float* __restrict__ x,
                                              const float* __restrict__ cores,
                                              const float* __restrict__ proj,
                                              float* __restrict__ ws) {
    const int blk = blockIdx.x;
    const int t   = threadIdx.x;

    if (blk < NSEG) {
        // ---- role A: segment product M = C[16s] @ ... @ C[16s+15]
        // State held in REGISTERS: thread (par,cg,l) holds M[l][cg*4 .. cg*4+3]
        // (replicated across the par twins). par splits the k-reduction into
        // halves k=0..15 / k=16..31; twins combine via shfl_xor(1).
        // Row l depends only on row l -> each wave owns 4 rows, NO barriers
        // inside the 15-step chain.
        __shared__ float Craw[SEGLEN * 1024];
        const float* cbase = cores + (size_t)blk * (SEGLEN * 1024);
        #pragma unroll
        for (int j = 0; j < 8; ++j) {
            int f = j * 2048 + t * 4;
            *(float4*)&Craw[f] = *(const float4*)(cbase + f);
        }
        __syncthreads();

        const int par = t & 1;            // k-half: 0 -> k=0..15, 1 -> k=16..31
        const int cg  = (t >> 1) & 7;     // column group (4 cols)
        const int c0  = cg << 2;
        const int l   = t >> 4;           // 0..31 (4 rows per wave)
        const int llo = (t >> 4) & 3;     // row within wave
        // holder of M[l][k]: lane (llo<<4) | ((k>>2)<<1) | par, register k&3.
        // k = 16*par + j  ->  srcLane = llo*16 + 9*par + 2*(j>>2)
        const int srcBase = (llo << 4) + par * 9;

        float4 ini = *(const float4*)&Craw[l * 32 + c0];   // M = C_0
        float s0 = ini.x, s1 = ini.y, s2 = ini.z, s3 = ini.w;

        for (int i = 1; i < SEGLEN; ++i) {
            const float* Ci = &Craw[i * 1024 + (par << 9)];  // rows 16*par ..
            float a0 = 0.f, a1 = 0.f, a2 = 0.f, a3 = 0.f;
            #pragma unroll
            for (int j = 0; j < 16; ++j) {
                const float sv = ((j & 3) == 0) ? s0
                               : ((j & 3) == 1) ? s1
                               : ((j & 3) == 2) ? s2 : s3;
                const float pv = __shfl(sv, srcBase + ((j >> 2) << 1), 64);
                const float4 cv = *(const float4*)&Ci[j * 32 + c0];
                a0 = fmaf(pv, cv.x, a0);
                a1 = fmaf(pv, cv.y, a1);
                a2 = fmaf(pv, cv.z, a2);
                a3 = fmaf(pv, cv.w, a3);
            }
            // combine k-halves across the par twins (lanes differ in bit 0)
            s0 = a0 + __shfl_xor(a0, 1, 64);
            s1 = a1 + __shfl_xor(a1, 1, 64);
            s2 = a2 + __shfl_xor(a2, 1, 64);
            s3 = a3 + __shfl_xor(a3, 1, 64);
        }
        if (par == 0)
            *(float4*)(ws + blk * 1024 + l * 32 + c0) = make_float4(s0, s1, s2, s3);

    } else if (blk < NSEG + 32) {
        // ---- role B: P2[r,o] = sum_l proj[r,l,o]  (unchanged)
        const int e = (blk - NSEG) * 512 + t;
        const int r = e >> 9;
        const int o = e & 511;
        float s0 = 0.f, s1 = 0.f, s2 = 0.f, s3 = 0.f;
        #pragma unroll
        for (int l = 0; l < 32; l += 4) {
            s0 += proj[(size_t)(r * 32 + l) * 512 + o];
            s1 += proj[(size_t)(r * 32 + l + 1) * 512 + o];
            s2 += proj[(size_t)(r * 32 + l + 2) * 512 + o];
            s3 += proj[(size_t)(r * 32 + l + 3) * 512 + o];
        }
        ws[16384 + e] = (s0 + s1) + (s2 + s3);

    } else {
        // ---- role C: s[b] = prod_i x[b,i]; one 64-lane wave per batch row
        const int wave = t >> 6;
        const int lane = t & 63;
        const int b    = (blk - (NSEG + 32)) * 8 + wave;
        float4 v = *(const float4*)(x + (size_t)b * 256 + lane * 4);
        float p = v.x * v.y * v.z * v.w;
        #pragma unroll
        for (int off = 32; off >= 1; off >>= 1)
            p *= __shfl_xor(p, off, 64);
        if (lane == 0) ws[32768 + b] = p;
    }
}

__global__ __launch_bounds__(512) void mps_k2(const float* __restrict__ ws,
                                              const float* __restrict__ bias,
                                              float* __restrict__ out) {
    __shared__ float u_sh[32];
    const int t = threadIdx.x;
    const float* P2 = ws + 16384;

    // issue P2 loads early (all waves) -> latency hides under the fold
    float p[32];
    #pragma unroll
    for (int r = 0; r < 32; ++r) p[r] = P2[r * 512 + t];

    if (t < 64) {
        // fold u^T = 1^T M_0 ... M_15 straight from L2, u replicated in regs.
        // halves: lanes 0-31 rows 0..15, lanes 32-63 rows 16..31.
        const int h  = t >> 5;
        const int c  = t & 31;
        const int rb = h << 4;                 // 16*h
        float cur[16];
        #pragma unroll
        for (int j = 0; j < 16; ++j) cur[j] = ws[(rb + j) * 32 + c];  // M0
        float a0 = 0.f, a1 = 0.f, a2 = 0.f, a3 = 0.f;
        #pragma unroll
        for (int j = 0; j < 16; j += 4) {
            a0 += cur[j]; a1 += cur[j + 1]; a2 += cur[j + 2]; a3 += cur[j + 3];
        }
        float u = (a0 + a1) + (a2 + a3);
        u += __shfl_xor(u, 32, 64);            // u = 1^T M0, replicated

        #pragma unroll
        for (int j = 0; j < 16; ++j) cur[j] = ws[1024 + (rb + j) * 32 + c];  // M1
        #pragma unroll
        for (int i = 1; i < 16; ++i) {
            float nxt[16];
            if (i < 15) {                      // prefetch M_{i+1}
                #pragma unroll
                for (int j = 0; j < 16; ++j)
                    nxt[j] = ws[(i + 1) * 1024 + (rb + j) * 32 + c];
            }
            float b0 = 0.f, b1 = 0.f, b2 = 0.f, b3 = 0.f;
            #pragma unroll
            for (int j = 0; j < 16; j += 4) {
                b0 = fmaf(__shfl(u, rb + j,     64), cur[j],     b0);
                b1 = fmaf(__shfl(u, rb + j + 1, 64), cur[j + 1], b1);
                b2 = fmaf(__shfl(u, rb + j + 2, 64), cur[j + 2], b2);
                b3 = fmaf(__shfl(u, rb + j + 3, 64), cur[j + 3], b3);
            }
            float un = (b0 + b1) + (b2 + b3);
            un += __shfl_xor(un, 32, 64);
            u = un;
            if (i < 15) {
                #pragma unroll
                for (int j = 0; j < 16; ++j) cur[j] = nxt[j];
            }
        }
        if (t < 32) u_sh[t] = u;
    }
    __syncthreads();

    // q[t] = sum_r u[r] * P2[r,t]; then 8 output rows per block
    float q0 = 0.f, q1 = 0.f, q2 = 0.f, q3 = 0.f;
    #pragma unroll
    for (int r = 0; r < 32; r += 4) {
        q0 = fmaf(u_sh[r],     p[r],     q0);
        q1 = fmaf(u_sh[r + 1], p[r + 1], q1);
        q2 = fmaf(u_sh[r + 2], p[r + 2], q2);
        q3 = fmaf(u_sh[r + 3], p[r + 3], q3);
    }
    const float qv = (q0 + q1) + (q2 + q3);
    const float bv = bias[t];

    const int b0i = blockIdx.x * 8;
    #pragma unroll
    for (int j = 0; j < 8; ++j) {
        const float s = ws[32768 + b0i + j];
        out[(size_t)(b0i + j) * 512 + t] = fmaf(s, qv, bv);
    }
}

extern "C" void kernel_launch(void* const* d_in, const int* in_sizes, int n_in,
                              void* d_out, int out_size, void* d_ws, size_t ws_size,
                              hipStream_t stream) {
    const float* x     = (const float*)d_in[0];   // [1024, 256]
    const float* cores = (const float*)d_in[1];   // [256, 32, 32]
    const float* proj  = (const float*)d_in[2];   // [32, 32, 512]
    const float* bias  = (const float*)d_in[3];   // [512]
    float* out = (float*)d_out;                    // [1024, 512]
    float* ws  = (float*)d_ws;

    hipLaunchKernelGGL(mps_k1, dim3(NSEG + 32 + 128), dim3(512), 0, stream,
                       x, cores, proj, ws);
    hipLaunchKernelGGL(mps_k2, dim3(128), dim3(512), 0, stream, ws, bias, out);
}